// Round 12
// baseline (34.058 us; speedup 1.0000x reference)
//
#include <hip/hip_runtime.h>
#include <hip/hip_bf16.h>

// SpreadGNN on MI355X (gfx950).
// Fully-connected per-graph edges => segment mean == per-graph mean:
//   h+ = relu( Wl * mean_g(h) + b + Wr * h ), x3, then out = Wp * mean_g(h3) + bp.
// One wave == one graph (32 nodes), activations f-major G[f][node].
// Round 11 == Round 9 resubmitted again (container unresponsive twice):
// SINGLE kernel, no prep pass, no d_ws. A-frag k-mapping = natural
// (k = ks*32 + 8g + j), matching the B-side from rb — so A-fragments read
// DIRECTLY from raw row-major f32 weights (2x dwordx4 + cvt). W1/W2 frags
// per-wave from L2$; W3 (64KB bf16) copy-cvt-staged into LDS once per block
// (coalesced, linear), one __syncthreads before L3. Activations bf16 in
// rb [32][136] (272B rows: 16B-aligned, bank-phase rotates per node).

typedef float f32x4 __attribute__((ext_vector_type(4)));
typedef __bf16 bf16x8 __attribute__((ext_vector_type(8)));
typedef unsigned short u16x4 __attribute__((ext_vector_type(4)));

__device__ __forceinline__ f32x4 MFMA(bf16x8 a, bf16x8 b, f32x4 c) {
  return __builtin_amdgcn_mfma_f32_16x16x32_bf16(a, b, c, 0, 0, 0);
}

__device__ __forceinline__ unsigned short bfbits(float v) {
  __hip_bfloat16 t = __float2bfloat16(v);   // RNE
  return __builtin_bit_cast(unsigned short, t);
}

__device__ __forceinline__ u16x4 pack4(f32x4 v) {
  u16x4 r;
  r[0] = bfbits(v[0]); r[1] = bfbits(v[1]);
  r[2] = bfbits(v[2]); r[3] = bfbits(v[3]);
  return r;
}

__device__ __forceinline__ bf16x8 pack8(f32x4 lo, f32x4 hi) {
  union { bf16x8 v; unsigned short u[8]; } t;
  t.u[0] = bfbits(lo[0]); t.u[1] = bfbits(lo[1]);
  t.u[2] = bfbits(lo[2]); t.u[3] = bfbits(lo[3]);
  t.u[4] = bfbits(hi[0]); t.u[5] = bfbits(hi[1]);
  t.u[6] = bfbits(hi[2]); t.u[7] = bfbits(hi[3]);
  return t.v;
}

#define RBW 136   // bf16 row stride: 272 B, 16B-aligned, bank-phase rotates
#define W3ROWS 256  // W3r rows 0..127, W3l rows 128..255

// ---- fused GNN: 1 wave = 1 graph, 8 waves/block, single kernel -------------
__global__ __launch_bounds__(512) void gnn_all(
    const float* __restrict__ obs,
    const float* __restrict__ W1l, const float* __restrict__ W1r,
    const float* __restrict__ W2l, const float* __restrict__ W2r,
    const float* __restrict__ W3l, const float* __restrict__ W3r,
    const float* __restrict__ b1, const float* __restrict__ b2,
    const float* __restrict__ b3,
    const float* __restrict__ Wp, const float* __restrict__ bp,
    float* __restrict__ out)
{
  __shared__ unsigned short smw3[W3ROWS * RBW];   // 69.6 KB bf16 W3 (r then l)
  __shared__ unsigned short rb_all[8][32 * RBW];  // 69.6 KB bf16 activations
  __shared__ unsigned short mb_all[8][128];       // bf16 means (Bg frags)
  __shared__ float mbf_all[8][128];               // f32 pooled (head)

  const int tid  = threadIdx.x;
  const int wid  = tid >> 6;     // 0..7
  const int lane = tid & 63;
  const int g    = lane >> 4;    // 4 groups of 16
  const int c    = lane & 15;    // node-col within tile
  unsigned short* rbb = &rb_all[wid][0];
  unsigned short* mbb = &mb_all[wid][0];
  float* mbf = &mbf_all[wid][0];
  const int graph = blockIdx.x * 8 + wid;
  const float* xg = obs + graph * 160;

  // ---- L1-critical loads first (head of the dependency chain) ----
  float x0[5], x1[5];
#pragma unroll
  for (int j = 0; j < 5; ++j) { x0[j] = xg[c * 5 + j]; x1[j] = xg[80 + c * 5 + j]; }

  // W1 frags: f = ft*16+c, k = 8g+j (K=5 -> only g==0, j<5 nonzero)
  bf16x8 ar1[4], al1[4];
#pragma unroll
  for (int ft = 0; ft < 4; ++ft) {
    float wr[8] = {0,0,0,0,0,0,0,0}, wl[8] = {0,0,0,0,0,0,0,0};
    if (g == 0) {
#pragma unroll
      for (int j = 0; j < 5; ++j) {
        wr[j] = W1r[(ft * 16 + c) * 5 + j];
        wl[j] = W1l[(ft * 16 + c) * 5 + j];
      }
    }
    f32x4 rlo = {wr[0], wr[1], wr[2], wr[3]}, rhi = {wr[4], 0.f, 0.f, 0.f};
    f32x4 llo = {wl[0], wl[1], wl[2], wl[3]}, lhi = {wl[4], 0.f, 0.f, 0.f};
    ar1[ft] = pack8(rlo, rhi);
    al1[ft] = pack8(llo, lhi);
  }

  // ---- W3 copy-cvt staging: 2 threads per row, coalesced ----
  {
    const int row  = tid >> 1;                     // 0..255
    const int half = tid & 1;                      // 64-elem half of the row
    const float* src = ((row < 128) ? (W3r + row * 128)
                                    : (W3l + (row - 128) * 128)) + half * 64;
    unsigned short* dst = smw3 + row * RBW + half * 64;
#pragma unroll
    for (int i = 0; i < 8; ++i) {
      f32x4 lo = *(const f32x4*)(src + i * 8);
      f32x4 hi = *(const f32x4*)(src + i * 8 + 4);
      *(bf16x8*)(dst + i * 8) = pack8(lo, hi);
    }
  }

  const f32x4 Z4 = {0.f, 0.f, 0.f, 0.f};

  // ---------------- Layer 1 (5 -> 64) ----------------
  float m0[5];
#pragma unroll
  for (int j = 0; j < 5; ++j) {
    float s = x0[j] + x1[j];
    s += __shfl_xor(s, 1, 64); s += __shfl_xor(s, 2, 64);
    s += __shfl_xor(s, 4, 64); s += __shfl_xor(s, 8, 64);
    m0[j] = s * 0.03125f;
  }
  bf16x8 Bn1[2], Bg1;
  {
    f32x4 a0 = {x0[0], x0[1], x0[2], x0[3]}, a1 = {x0[4], 0.f, 0.f, 0.f};
    f32x4 n0 = {x1[0], x1[1], x1[2], x1[3]}, n1 = {x1[4], 0.f, 0.f, 0.f};
    f32x4 g0 = {m0[0], m0[1], m0[2], m0[3]}, g1 = {m0[4], 0.f, 0.f, 0.f};
    if (g != 0) { a0 = Z4; a1 = Z4; n0 = Z4; n1 = Z4; g0 = Z4; g1 = Z4; }
    Bn1[0] = pack8(a0, a1); Bn1[1] = pack8(n0, n1); Bg1 = pack8(g0, g1);
  }

  f32x4 acc[2][8];
#pragma unroll
  for (int ft = 0; ft < 4; ++ft) {
    f32x4 bias = *(const f32x4*)(b1 + ft * 16 + 4 * g);
    acc[0][ft] = bias; acc[1][ft] = bias;
    acc[0][ft] = MFMA(ar1[ft], Bn1[0], acc[0][ft]);
    acc[1][ft] = MFMA(ar1[ft], Bn1[1], acc[1][ft]);
    acc[0][ft] = MFMA(al1[ft], Bg1, acc[0][ft]);
    acc[1][ft] = MFMA(al1[ft], Bg1, acc[1][ft]);
  }
#pragma unroll
  for (int ct = 0; ct < 2; ++ct)
#pragma unroll
    for (int ft = 0; ft < 4; ++ft)
#pragma unroll
      for (int i = 0; i < 4; ++i)
        acc[ct][ft][i] = fmaxf(acc[ct][ft][i], 0.f);

  // L1 epilogue: bf16 writes + reg-fold means (f in [0,64))
#pragma unroll
  for (int ft = 0; ft < 4; ++ft) {
    *(u16x4*)(rbb + c * RBW        + ft * 16 + 4 * g) = pack4(acc[0][ft]);
    *(u16x4*)(rbb + (16 + c) * RBW + ft * 16 + 4 * g) = pack4(acc[1][ft]);
    f32x4 s = acc[0][ft] + acc[1][ft];
#pragma unroll
    for (int i = 0; i < 4; ++i) {
      float v = s[i];
      v += __shfl_xor(v, 1, 64); v += __shfl_xor(v, 2, 64);
      v += __shfl_xor(v, 4, 64); v += __shfl_xor(v, 8, 64);
      s[i] = v * 0.03125f;
    }
    if (c == 0) *(u16x4*)(mbb + ft * 16 + 4 * g) = pack4(s);
  }

  // ---------------- Layer 2 (64 -> 128), A-frags raw f32 + cvt ------------
  bf16x8 Bn[2][4], Bg[4];
#pragma unroll
  for (int ct = 0; ct < 2; ++ct)
#pragma unroll
    for (int ks = 0; ks < 2; ++ks)
      Bn[ct][ks] = *(const bf16x8*)(rbb + (ct * 16 + c) * RBW + 32 * ks + 8 * g);
#pragma unroll
  for (int ks = 0; ks < 2; ++ks)
    Bg[ks] = *(const bf16x8*)(mbb + 32 * ks + 8 * g);

#pragma unroll
  for (int ft = 0; ft < 8; ++ft) {
    f32x4 bias = *(const f32x4*)(b2 + ft * 16 + 4 * g);
    acc[0][ft] = bias; acc[1][ft] = bias;
#pragma unroll
    for (int ks = 0; ks < 2; ++ks) {
      const float* pr = W2r + (ft * 16 + c) * 64 + ks * 32 + 8 * g;
      const float* pl = W2l + (ft * 16 + c) * 64 + ks * 32 + 8 * g;
      bf16x8 ar = pack8(*(const f32x4*)pr, *(const f32x4*)(pr + 4));
      bf16x8 al = pack8(*(const f32x4*)pl, *(const f32x4*)(pl + 4));
      acc[0][ft] = MFMA(ar, Bn[0][ks], acc[0][ft]);
      acc[1][ft] = MFMA(ar, Bn[1][ks], acc[1][ft]);
      acc[0][ft] = MFMA(al, Bg[ks], acc[0][ft]);
      acc[1][ft] = MFMA(al, Bg[ks], acc[1][ft]);
    }
  }
#pragma unroll
  for (int ct = 0; ct < 2; ++ct)
#pragma unroll
    for (int ft = 0; ft < 8; ++ft)
#pragma unroll
      for (int i = 0; i < 4; ++i)
        acc[ct][ft][i] = fmaxf(acc[ct][ft][i], 0.f);

  // L2 epilogue: bf16 writes + reg-fold means (f in [0,128))
#pragma unroll
  for (int ft = 0; ft < 8; ++ft) {
    *(u16x4*)(rbb + c * RBW        + ft * 16 + 4 * g) = pack4(acc[0][ft]);
    *(u16x4*)(rbb + (16 + c) * RBW + ft * 16 + 4 * g) = pack4(acc[1][ft]);
    f32x4 s = acc[0][ft] + acc[1][ft];
#pragma unroll
    for (int i = 0; i < 4; ++i) {
      float v = s[i];
      v += __shfl_xor(v, 1, 64); v += __shfl_xor(v, 2, 64);
      v += __shfl_xor(v, 4, 64); v += __shfl_xor(v, 8, 64);
      s[i] = v * 0.03125f;
    }
    if (c == 0) *(u16x4*)(mbb + ft * 16 + 4 * g) = pack4(s);
  }

  // ---- staged W3 must be visible to all waves ----
  __syncthreads();

  // ---------------- Layer 3 (128 -> 128), weights from LDS ----------------
  {
    const unsigned short* A3r = smw3;                // rows 0..127
    const unsigned short* A3l = smw3 + 128 * RBW;    // rows 128..255
#pragma unroll
    for (int ct = 0; ct < 2; ++ct)
#pragma unroll
      for (int ks = 0; ks < 4; ++ks)
        Bn[ct][ks] = *(const bf16x8*)(rbb + (ct * 16 + c) * RBW + 32 * ks + 8 * g);
#pragma unroll
    for (int ks = 0; ks < 4; ++ks)
      Bg[ks] = *(const bf16x8*)(mbb + 32 * ks + 8 * g);

#pragma unroll
    for (int ft = 0; ft < 8; ++ft) {
      f32x4 bias = *(const f32x4*)(b3 + ft * 16 + 4 * g);
      acc[0][ft] = bias; acc[1][ft] = bias;
#pragma unroll
      for (int ks = 0; ks < 4; ++ks) {
        bf16x8 ar = *(const bf16x8*)(A3r + (ft * 16 + c) * RBW + ks * 32 + 8 * g);
        bf16x8 al = *(const bf16x8*)(A3l + (ft * 16 + c) * RBW + ks * 32 + 8 * g);
        acc[0][ft] = MFMA(ar, Bn[0][ks], acc[0][ft]);
        acc[1][ft] = MFMA(ar, Bn[1][ks], acc[1][ft]);
        acc[0][ft] = MFMA(al, Bg[ks], acc[0][ft]);
        acc[1][ft] = MFMA(al, Bg[ks], acc[1][ft]);
      }
    }
  }
#pragma unroll
  for (int ct = 0; ct < 2; ++ct)
#pragma unroll
    for (int ft = 0; ft < 8; ++ft)
#pragma unroll
      for (int i = 0; i < 4; ++i)
        acc[ct][ft][i] = fmaxf(acc[ct][ft][i], 0.f);

  // L3 epilogue: pooled means only -> mbf (f32 throughout; no rb writes)
#pragma unroll
  for (int ft = 0; ft < 8; ++ft) {
    f32x4 s = acc[0][ft] + acc[1][ft];
#pragma unroll
    for (int i = 0; i < 4; ++i) {
      float v = s[i];
      v += __shfl_xor(v, 1, 64); v += __shfl_xor(v, 2, 64);
      v += __shfl_xor(v, 4, 64); v += __shfl_xor(v, 8, 64);
      s[i] = v * 0.03125f;
    }
    if (c == 0) *(f32x4*)(mbf + ft * 16 + 4 * g) = s;
  }

  // ---------------- head: out = Wp * pooled + bp (f32) ----------------
  float p0 = mbf[lane], p1 = mbf[64 + lane];
  float po[5];
#pragma unroll
  for (int o = 0; o < 5; ++o)
    po[o] = p0 * Wp[o * 128 + lane] + p1 * Wp[o * 128 + 64 + lane];
#pragma unroll
  for (int o = 0; o < 5; ++o) {
    float v = po[o];
    v += __shfl_xor(v, 1, 64);  v += __shfl_xor(v, 2, 64);
    v += __shfl_xor(v, 4, 64);  v += __shfl_xor(v, 8, 64);
    v += __shfl_xor(v, 16, 64); v += __shfl_xor(v, 32, 64);
    po[o] = v;
  }
  if (lane == 0) {
#pragma unroll
    for (int o = 0; o < 5; ++o) out[graph * 5 + o] = po[o] + bp[o];
  }
}

extern "C" void kernel_launch(void* const* d_in, const int* in_sizes, int n_in,
                              void* d_out, int out_size, void* d_ws, size_t ws_size,
                              hipStream_t stream)
{
  const float* obs = (const float*)d_in[0];
  // d_in[1]=src, d_in[2]=dst: fully-connected per-graph -> segment mean; unused.
  const float* W1l = (const float*)d_in[3];
  const float* b1  = (const float*)d_in[4];
  const float* W1r = (const float*)d_in[5];
  const float* W2l = (const float*)d_in[6];
  const float* b2  = (const float*)d_in[7];
  const float* W2r = (const float*)d_in[8];
  const float* W3l = (const float*)d_in[9];
  const float* b3  = (const float*)d_in[10];
  const float* W3r = (const float*)d_in[11];
  const float* Wp  = (const float*)d_in[12];
  const float* bp  = (const float*)d_in[13];
  float* out = (float*)d_out;

  gnn_all<<<256, 512, 0, stream>>>(obs, W1l, W1r, W2l, W2r, W3l, W3r,
                                   b1, b2, b3, Wp, bp, out);
}

// Round 13
// 22.853 us; speedup vs baseline: 1.4903x; 1.4903x over previous
//
#include <hip/hip_runtime.h>
#include <hip/hip_bf16.h>

// SpreadGNN on MI355X (gfx950).
// Fully-connected per-graph edges => segment mean == per-graph mean:
//   h+ = relu( Wl * mean_g(h) + b + Wr * h ), x3, then out = Wp * mean_g(h3) + bp.
// One wave == one graph (32 nodes), activations f-major G[f][node].
// Round 13: R1 skeleton (22.0us best) + REGISTER PRELOAD of all A1+A2
// fragments at kernel head. R12's profile showed the true bottleneck:
// MfmaUtil 0.7%, VGPR 88 -> ~100 weight-fragment loads serialized at L2
// latency (~300cy each) with nothing in flight. Preloading 40 independent
// 16B loads up front + __launch_bounds__(512,2) (VGPR cap 256) converts the
// serial chain into one pipelined burst. A3 still DMA-staged to LDS (drain
// before L3). Epilogue identical to R1 (f32 rb, stride 68).

typedef float f32x4 __attribute__((ext_vector_type(4)));
typedef __bf16 bf16x8 __attribute__((ext_vector_type(8)));

__device__ __forceinline__ f32x4 MFMA(bf16x8 a, bf16x8 b, f32x4 c) {
  return __builtin_amdgcn_mfma_f32_16x16x32_bf16(a, b, c, 0, 0, 0);
}

__device__ __forceinline__ unsigned short bfbits(float v) {
  __hip_bfloat16 t = __float2bfloat16(v);   // RNE
  return __builtin_bit_cast(unsigned short, t);
}

__device__ __forceinline__ bf16x8 pack8(f32x4 lo, f32x4 hi) {
  union { bf16x8 v; unsigned short u[8]; } t;
  t.u[0] = bfbits(lo[0]); t.u[1] = bfbits(lo[1]);
  t.u[2] = bfbits(lo[2]); t.u[3] = bfbits(lo[3]);
  t.u[4] = bfbits(hi[0]); t.u[5] = bfbits(hi[1]);
  t.u[6] = bfbits(hi[2]); t.u[7] = bfbits(hi[3]);
  return t.v;
}

// ---- weight prep: pack W[f][k] (f32) -> bf16 A-fragments -------------------
// pack element index: ((ft*KS + ks)*64 + lane)*8 + j
//   f = ft*16 + (lane&15),  k = ks*32 + (lane>>4)*8 + j,  0 if k >= Kreal
// segments (elements): A1r[0,2048) A1l[2048,4096) A2r[4096,12288)
//   A2l[12288,20480) A3r[20480,36864) A3l[36864,53248)
__global__ __launch_bounds__(256) void gnn_prep(
    const float* __restrict__ W1l, const float* __restrict__ W1r,
    const float* __restrict__ W2l, const float* __restrict__ W2r,
    const float* __restrict__ W3l, const float* __restrict__ W3r,
    unsigned short* __restrict__ wpack)
{
  int e = blockIdx.x * 256 + threadIdx.x;
  if (e >= 53248) return;
  const float* src; int Kreal, KS, eloc;
  if      (e < 2048)  { src = W1r; Kreal = 5;   KS = 1; eloc = e; }
  else if (e < 4096)  { src = W1l; Kreal = 5;   KS = 1; eloc = e - 2048; }
  else if (e < 12288) { src = W2r; Kreal = 64;  KS = 2; eloc = e - 4096; }
  else if (e < 20480) { src = W2l; Kreal = 64;  KS = 2; eloc = e - 12288; }
  else if (e < 36864) { src = W3r; Kreal = 128; KS = 4; eloc = e - 20480; }
  else                { src = W3l; Kreal = 128; KS = 4; eloc = e - 36864; }
  int j = eloc & 7, lane = (eloc >> 3) & 63, rest = eloc >> 9;
  int ks = rest % KS, ft = rest / KS;
  int f = ft * 16 + (lane & 15);
  int k = ks * 32 + (lane >> 4) * 8 + j;
  float v = (k < Kreal) ? src[f * Kreal + k] : 0.f;
  wpack[e] = bfbits(v);
}

// ---- fused GNN: 1 wave = 1 graph, 8 waves/block, A3 in LDS -----------------
__global__ __launch_bounds__(512, 2) void gnn_fused(
    const float* __restrict__ obs,
    const float* __restrict__ b1, const float* __restrict__ b2,
    const float* __restrict__ b3,
    const float* __restrict__ Wp, const float* __restrict__ bp,
    const unsigned short* __restrict__ wpack,
    float* __restrict__ out)
{
  __shared__ unsigned short smA3[32768];       // A3r [0,16384) A3l [16384,32768)
  __shared__ float rb_all[8][32 * 68];
  __shared__ float mb_all[8][128];

  const int tid  = threadIdx.x;
  const int wid  = tid >> 6;     // 0..7
  const int lane = tid & 63;
  const int g    = lane >> 4;    // 4 groups of 16
  const int c    = lane & 15;    // node-col within tile
  float* rb = &rb_all[wid][0];
  float* mb = &mb_all[wid][0];
  const int graph = blockIdx.x * 8 + wid;
  const float* xg = obs + graph * 160;

  const unsigned short* A1r = wpack;
  const unsigned short* A1l = wpack + 2048;
  const unsigned short* A2r = wpack + 4096;
  const unsigned short* A2l = wpack + 12288;

  // ======== PRELOAD PHASE: 40 independent VMEM loads, all in flight ========
  // obs first (head of the L1 chain)
  float x0[5], x1[5];
#pragma unroll
  for (int j = 0; j < 5; ++j) { x0[j] = xg[c * 5 + j]; x1[j] = xg[80 + c * 5 + j]; }

  // A1: 8 fragments (32 VGPR)
  bf16x8 a1r[4], a1l[4];
#pragma unroll
  for (int ft = 0; ft < 4; ++ft) {
    a1r[ft] = *(const bf16x8*)(A1r + (ft * 64 + lane) * 8);
    a1l[ft] = *(const bf16x8*)(A1l + (ft * 64 + lane) * 8);
  }
  // A2: 32 fragments (128 VGPR), held through L2
  bf16x8 a2r[16], a2l[16];
#pragma unroll
  for (int ft = 0; ft < 8; ++ft)
#pragma unroll
    for (int ks = 0; ks < 2; ++ks) {
      a2r[ft * 2 + ks] = *(const bf16x8*)(A2r + ((ft * 2 + ks) * 64 + lane) * 8);
      a2l[ft * 2 + ks] = *(const bf16x8*)(A2l + ((ft * 2 + ks) * 64 + lane) * 8);
    }

  // ---- issue A3 staging: 64 chunks x 1KB, 8 per wave (DMA, no VALU) ----
  {
    const unsigned short* gA3 = wpack + 20480;
#pragma unroll
    for (int it = 0; it < 8; ++it) {
      const int chunk = it * 8 + wid;   // wave-uniform
      const void* gsrc = (const void*)((const char*)(gA3 + chunk * 512) + lane * 16);
      __builtin_amdgcn_global_load_lds(
          (const __attribute__((address_space(1))) unsigned int*)gsrc,
          (__attribute__((address_space(3))) unsigned int*)&smA3[chunk * 512],
          16, 0, 0);
    }
  }

  const f32x4 Z4 = {0.f, 0.f, 0.f, 0.f};

  // ---------------- Layer 1 (5 -> 64) ----------------
  float m0[5];
#pragma unroll
  for (int j = 0; j < 5; ++j) {
    float s = x0[j] + x1[j];
    s += __shfl_xor(s, 1, 64); s += __shfl_xor(s, 2, 64);
    s += __shfl_xor(s, 4, 64); s += __shfl_xor(s, 8, 64);
    m0[j] = s * 0.03125f;
  }
  bf16x8 Bn1[2], Bg1;
  {
    f32x4 a0 = {x0[0], x0[1], x0[2], x0[3]}, a1 = {x0[4], 0.f, 0.f, 0.f};
    f32x4 n0 = {x1[0], x1[1], x1[2], x1[3]}, n1 = {x1[4], 0.f, 0.f, 0.f};
    f32x4 g0 = {m0[0], m0[1], m0[2], m0[3]}, g1 = {m0[4], 0.f, 0.f, 0.f};
    if (g != 0) { a0 = Z4; a1 = Z4; n0 = Z4; n1 = Z4; g0 = Z4; g1 = Z4; }
    Bn1[0] = pack8(a0, a1); Bn1[1] = pack8(n0, n1); Bg1 = pack8(g0, g1);
  }

  f32x4 acc[2][8];
#pragma unroll
  for (int ft = 0; ft < 4; ++ft) {
    f32x4 bias = *(const f32x4*)(b1 + ft * 16 + 4 * g);
    acc[0][ft] = bias; acc[1][ft] = bias;
    acc[0][ft] = MFMA(a1r[ft], Bn1[0], acc[0][ft]);
    acc[1][ft] = MFMA(a1r[ft], Bn1[1], acc[1][ft]);
    acc[0][ft] = MFMA(a1l[ft], Bg1, acc[0][ft]);
    acc[1][ft] = MFMA(a1l[ft], Bg1, acc[1][ft]);
  }
#pragma unroll
  for (int ct = 0; ct < 2; ++ct)
#pragma unroll
    for (int ft = 0; ft < 4; ++ft)
#pragma unroll
      for (int i = 0; i < 4; ++i)
        acc[ct][ft][i] = fmaxf(acc[ct][ft][i], 0.f);

  // L1 epilogue: transpose via rb, mean -> mb[0..63], build next frags
  bf16x8 Bn2[2][2], Bg2[2];
  {
#pragma unroll
    for (int ct = 0; ct < 2; ++ct)
#pragma unroll
      for (int ft = 0; ft < 4; ++ft)
        *(f32x4*)(rb + (ct * 16 + c) * 68 + ft * 16 + 4 * g) = acc[ct][ft];
    f32x4 sum = Z4;
#pragma unroll
    for (int cc = 0; cc < 8; ++cc)
      sum += *(const f32x4*)(rb + (g * 8 + cc) * 68 + c * 4);
#pragma unroll
    for (int i = 0; i < 4; ++i) {
      float v = sum[i];
      v += __shfl_xor(v, 16, 64); v += __shfl_xor(v, 32, 64);
      sum[i] = v * 0.03125f;
    }
    if (g == 0) *(f32x4*)(mb + c * 4) = sum;
#pragma unroll
    for (int ct = 0; ct < 2; ++ct)
#pragma unroll
      for (int ks = 0; ks < 2; ++ks) {
        f32x4 lo = *(const f32x4*)(rb + (ct * 16 + c) * 68 + ks * 32 + 8 * g);
        f32x4 hi = *(const f32x4*)(rb + (ct * 16 + c) * 68 + ks * 32 + 8 * g + 4);
        Bn2[ct][ks] = pack8(lo, hi);
      }
#pragma unroll
    for (int ks = 0; ks < 2; ++ks) {
      f32x4 lo = *(const f32x4*)(mb + ks * 32 + 8 * g);
      f32x4 hi = *(const f32x4*)(mb + ks * 32 + 8 * g + 4);
      Bg2[ks] = pack8(lo, hi);
    }
  }

  // ---------------- Layer 2 (64 -> 128), weights from registers -----------
#pragma unroll
  for (int ft = 0; ft < 8; ++ft) {
    f32x4 bias = *(const f32x4*)(b2 + ft * 16 + 4 * g);
    acc[0][ft] = bias; acc[1][ft] = bias;
#pragma unroll
    for (int ks = 0; ks < 2; ++ks) {
      acc[0][ft] = MFMA(a2r[ft * 2 + ks], Bn2[0][ks], acc[0][ft]);
      acc[1][ft] = MFMA(a2r[ft * 2 + ks], Bn2[1][ks], acc[1][ft]);
      acc[0][ft] = MFMA(a2l[ft * 2 + ks], Bg2[ks], acc[0][ft]);
      acc[1][ft] = MFMA(a2l[ft * 2 + ks], Bg2[ks], acc[1][ft]);
    }
  }
#pragma unroll
  for (int ct = 0; ct < 2; ++ct)
#pragma unroll
    for (int ft = 0; ft < 8; ++ft)
#pragma unroll
      for (int i = 0; i < 4; ++i)
        acc[ct][ft][i] = fmaxf(acc[ct][ft][i], 0.f);

  // L2 epilogue: two f-halves through rb; mean -> mb[0..127]
  bf16x8 Bn3[2][4], Bg3[4];
#pragma unroll
  for (int h = 0; h < 2; ++h) {
#pragma unroll
    for (int ct = 0; ct < 2; ++ct)
#pragma unroll
      for (int q = 0; q < 4; ++q)
        *(f32x4*)(rb + (ct * 16 + c) * 68 + q * 16 + 4 * g) = acc[ct][4 * h + q];
    f32x4 sum = Z4;
#pragma unroll
    for (int cc = 0; cc < 8; ++cc)
      sum += *(const f32x4*)(rb + (g * 8 + cc) * 68 + c * 4);
#pragma unroll
    for (int i = 0; i < 4; ++i) {
      float v = sum[i];
      v += __shfl_xor(v, 16, 64); v += __shfl_xor(v, 32, 64);
      sum[i] = v * 0.03125f;
    }
    if (g == 0) *(f32x4*)(mb + 64 * h + c * 4) = sum;
#pragma unroll
    for (int ct = 0; ct < 2; ++ct)
#pragma unroll
      for (int k2 = 0; k2 < 2; ++k2) {
        f32x4 lo = *(const f32x4*)(rb + (ct * 16 + c) * 68 + k2 * 32 + 8 * g);
        f32x4 hi = *(const f32x4*)(rb + (ct * 16 + c) * 68 + k2 * 32 + 8 * g + 4);
        Bn3[ct][2 * h + k2] = pack8(lo, hi);
      }
  }
#pragma unroll
  for (int ks = 0; ks < 4; ++ks) {
    f32x4 lo = *(const f32x4*)(mb + ks * 32 + 8 * g);
    f32x4 hi = *(const f32x4*)(mb + ks * 32 + 8 * g + 4);
    Bg3[ks] = pack8(lo, hi);
  }

  // ---- staged A3 must be resident before L3 fragment reads ----
  asm volatile("s_waitcnt vmcnt(0)" ::: "memory");
  __syncthreads();

  // ---------------- Layer 3 (128 -> 128), weights from LDS ----------------
  {
    const unsigned short* A3r = smA3;           // [0,16384)
    const unsigned short* A3l = smA3 + 16384;   // [16384,32768)
#pragma unroll
    for (int ft = 0; ft < 8; ++ft) {
      f32x4 bias = *(const f32x4*)(b3 + ft * 16 + 4 * g);
      acc[0][ft] = bias; acc[1][ft] = bias;
#pragma unroll
      for (int ks = 0; ks < 4; ++ks) {
        bf16x8 ar = *(const bf16x8*)(A3r + ((ft * 4 + ks) * 64 + lane) * 8);
        bf16x8 al = *(const bf16x8*)(A3l + ((ft * 4 + ks) * 64 + lane) * 8);
        acc[0][ft] = MFMA(ar, Bn3[0][ks], acc[0][ft]);
        acc[1][ft] = MFMA(ar, Bn3[1][ks], acc[1][ft]);
        acc[0][ft] = MFMA(al, Bg3[ks], acc[0][ft]);
        acc[1][ft] = MFMA(al, Bg3[ks], acc[1][ft]);
      }
    }
  }
#pragma unroll
  for (int ct = 0; ct < 2; ++ct)
#pragma unroll
    for (int ft = 0; ft < 8; ++ft)
#pragma unroll
      for (int i = 0; i < 4; ++i)
        acc[ct][ft][i] = fmaxf(acc[ct][ft][i], 0.f);

  // L3 epilogue: pooled = mean(relu(h3)) -> mb (f32, never touches bf16)
#pragma unroll
  for (int h = 0; h < 2; ++h) {
#pragma unroll
    for (int ct = 0; ct < 2; ++ct)
#pragma unroll
      for (int q = 0; q < 4; ++q)
        *(f32x4*)(rb + (ct * 16 + c) * 68 + q * 16 + 4 * g) = acc[ct][4 * h + q];
    f32x4 sum = Z4;
#pragma unroll
    for (int cc = 0; cc < 8; ++cc)
      sum += *(const f32x4*)(rb + (g * 8 + cc) * 68 + c * 4);
#pragma unroll
    for (int i = 0; i < 4; ++i) {
      float v = sum[i];
      v += __shfl_xor(v, 16, 64); v += __shfl_xor(v, 32, 64);
      sum[i] = v * 0.03125f;
    }
    if (g == 0) *(f32x4*)(mb + 64 * h + c * 4) = sum;
  }

  // ---------------- head: out = Wp * pooled + bp (f32) ----------------
  float p0 = mb[lane], p1 = mb[64 + lane];
  float po[5];
#pragma unroll
  for (int o = 0; o < 5; ++o)
    po[o] = p0 * Wp[o * 128 + lane] + p1 * Wp[o * 128 + 64 + lane];
#pragma unroll
  for (int o = 0; o < 5; ++o) {
    float v = po[o];
    v += __shfl_xor(v, 1, 64);  v += __shfl_xor(v, 2, 64);
    v += __shfl_xor(v, 4, 64);  v += __shfl_xor(v, 8, 64);
    v += __shfl_xor(v, 16, 64); v += __shfl_xor(v, 32, 64);
    po[o] = v;
  }
  if (lane == 0) {
#pragma unroll
    for (int o = 0; o < 5; ++o) out[graph * 5 + o] = po[o] + bp[o];
  }
}

extern "C" void kernel_launch(void* const* d_in, const int* in_sizes, int n_in,
                              void* d_out, int out_size, void* d_ws, size_t ws_size,
                              hipStream_t stream)
{
  const float* obs = (const float*)d_in[0];
  // d_in[1]=src, d_in[2]=dst: fully-connected per-graph -> segment mean; unused.
  const float* W1l = (const float*)d_in[3];
  const float* b1  = (const float*)d_in[4];
  const float* W1r = (const float*)d_in[5];
  const float* W2l = (const float*)d_in[6];
  const float* b2  = (const float*)d_in[7];
  const float* W2r = (const float*)d_in[8];
  const float* W3l = (const float*)d_in[9];
  const float* b3  = (const float*)d_in[10];
  const float* W3r = (const float*)d_in[11];
  const float* Wp  = (const float*)d_in[12];
  const float* bp  = (const float*)d_in[13];
  unsigned short* wpack = (unsigned short*)d_ws;   // 104 KB of d_ws
  float* out = (float*)d_out;

  gnn_prep<<<208, 256, 0, stream>>>(W1l, W1r, W2l, W2r, W3l, W3r, wpack);
  gnn_fused<<<256, 512, 0, stream>>>(obs, b1, b2, b3, Wp, bp, wpack, out);
}